// Round 5
// baseline (984.298 us; speedup 1.0000x reference)
//
#include <hip/hip_runtime.h>
#include <math.h>

#define CCH 512
#define HW 4096
#define NN 32768
#define NE 8192

// ws layout (bytes)
#define WS_BT  0                         // BT bf16 fragment-order: 8192*512*2B = 8388608
#define WS_ZZ  (8388608)                 // zz f32 [32768]
#define WS_BM1 (WS_ZZ + 131072)          // blockmax v1 [32768][64] f32 = 8388608
#define WS_BM2 (WS_BM1 + 8388608)        // blockmax v2 [32768][64] f32
#define WS_BI1 (WS_BM2 + 8388608)        // blockmax i1 [32768][64] i32
#define WS_IDX (WS_BI1 + 8388608)        // final idx [32768] i32
#define WS_ACC (WS_IDX + 131072)         // accs[0]=loss num, accs[1]=wsum (f64)
// AT (bf16(2z) fragment-order, 32768*512*2B = 33.5MB) lives in d_out[0..8388608 floats):
// written by k_prep_a, last read by k_gemm, then overwritten by k_out. Sequential stream => safe.

// bf16-only GEMM: score error std ~2.7e-5; THRESH = 1e-3 >> 30 sigma guard.
#define THRESH 1.0e-3f

typedef __attribute__((ext_vector_type(8)))  short short8;   // 8 bf16 (4 VGPRs)
typedef __attribute__((ext_vector_type(16))) float f32x16;   // 32x32 MFMA acc

// ---------------- K0: cb -> BT bf16, fragment-linear layout; zero accs
// chunk(jt32, s): 64 lanes x 16B; lane l holds cb[j=jt*32+(l&31)][k=s*16+(l>>5)*8 + e], e=0..7
__global__ __launch_bounds__(256) void k_prep_b(const float* __restrict__ cb,
                                                unsigned short* __restrict__ BT,
                                                double* __restrict__ accs) {
    int t = blockIdx.x * 256 + threadIdx.x;
    if (t == 0) { accs[0] = 0.0; accs[1] = 0.0; }
    int l = t & 63, s = (t >> 6) & 31, jt = t >> 11;
    int j = jt * 32 + (l & 31);
    int kb = s * 16 + (l >> 5) * 8;
    short8 hv;
#pragma unroll
    for (int e = 0; e < 8; ++e) {
        float x = cb[(size_t)j * CCH + kb + e];
        hv[e] = (short)(__float_as_uint(x) >> 16);   // truncation to bf16
    }
    size_t chunk = (size_t)jt * 32 + s;
    *(short8*)&BT[chunk * 512 + (size_t)l * 8] = hv;
}

// ---------------- K0b: z -> AT = bf16(2z), same fragment-linear chunk layout as BT.
// chunk = mt*32+s; lane l holds 2z[m=mt*32+(l&31)][k=s*16+(l>>5)*8+e]
__global__ __launch_bounds__(256) void k_prep_a(const float* __restrict__ z,
                                                unsigned short* __restrict__ AT) {
    int t = blockIdx.x * 256 + threadIdx.x;
    int l = t & 63;
    int chunk = t >> 6;                  // [0, 32768)
    int mt = chunk >> 5, s = chunk & 31;
    int m = mt * 32 + (l & 31);
    int kb = s * 16 + (l >> 5) * 8;
    const float* zp = z + (size_t)(m >> 12) * CCH * HW + (m & 4095);
    short8 hv;
#pragma unroll
    for (int e = 0; e < 8; ++e) {
        float x = 2.0f * zp[(size_t)(kb + e) * HW];      // *2 exact (pow2)
        hv[e] = (short)(__float_as_uint(x) >> 16);       // truncation to bf16
    }
    *(short8*)&AT[(size_t)chunk * 512 + (size_t)l * 8] = hv;
}

// ---------------- K1: zz[n] = np.sum(zf*zf, axis=1), numpy's exact pairwise tree
__global__ __launch_bounds__(256) void k_zz(const float* __restrict__ z,
                                            float* __restrict__ zz) {
    int t = threadIdx.x;
    int n = blockIdx.x * 256 + t;
    int b = n >> 12, hw = n & 4095;
    const float* zp = z + (size_t)b * CCH * HW + hw;
    float blk[4];
#pragma unroll
    for (int q = 0; q < 4; ++q) {
        float r[8];
#pragma unroll
        for (int j = 0; j < 8; ++j) {
            float v = zp[(size_t)(q * 128 + j) * HW];
            r[j] = __fmul_rn(v, v);
        }
        for (int i = 8; i < 128; i += 8) {
#pragma unroll
            for (int j = 0; j < 8; ++j) {
                float v = zp[(size_t)(q * 128 + i + j) * HW];
                r[j] = __fadd_rn(r[j], __fmul_rn(v, v));
            }
        }
        blk[q] = __fadd_rn(__fadd_rn(__fadd_rn(r[0], r[1]), __fadd_rn(r[2], r[3])),
                           __fadd_rn(__fadd_rn(r[4], r[5]), __fadd_rn(r[6], r[7])));
    }
    zz[n] = __fadd_rn(__fadd_rn(blk[0], blk[1]), __fadd_rn(blk[2], blk[3]));
}

// ---------------- K2: wsum = sum(m==0)
__global__ __launch_bounds__(256) void k_wsum(const float* __restrict__ m,
                                              double* __restrict__ accs) {
    __shared__ int sc[4];
    int tid = threadIdx.x;
    int base = blockIdx.x * 1024;
    int cnt = 0;
#pragma unroll
    for (int k2 = 0; k2 < 4; ++k2) cnt += (m[base + k2 * 256 + tid] == 0.0f) ? 1 : 0;
#pragma unroll
    for (int o = 32; o; o >>= 1) cnt += __shfl_xor(cnt, o);
    if ((tid & 63) == 0) sc[tid >> 6] = cnt;
    __syncthreads();
    if (tid == 0) atomicAdd(&accs[1], (double)(sc[0] + sc[1] + sc[2] + sc[3]));
}

// ---------------- K3: LDS-FREE pre-packed bf16 MFMA GEMM.
// Both operands are fragment-linear in DRAM: every MFMA fragment is one coalesced
// per-lane dwordx4 at chunkBase + s*1024 + l*16. Load straight L2->VGPR with a 2-deep
// register double buffer. No LDS, no barriers; waves fully independent.
// Block 128m x 256n, 4 waves (2x2), wave tile 64x128 (2x4 frags of 32x32).
__global__ __launch_bounds__(256, 2) void k_gemm(const unsigned short* __restrict__ AT,
                                                 const unsigned short* __restrict__ BT,
                                                 float* __restrict__ bm1,
                                                 float* __restrict__ bm2,
                                                 int* __restrict__ bi1) {
    int tid = threadIdx.x;
    int l = tid & 63;
    int gq = tid >> 6;             // wave id
    int wm = gq & 1, wn = gq >> 1; // 2x2 wave grid
    int nb = blockIdx.x & 31, mb = blockIdx.x >> 5;
    int khalf = l >> 5;

    // fragment-linear chunk bases (per-lane): row-tile chunks of 32 rows, 32 k-slices each
    const char* aBase0 = (const char*)AT + (size_t)(mb * 4 + wm * 2 + 0) * 32768 + (size_t)l * 16;
    const char* aBase1 = (const char*)AT + (size_t)(mb * 4 + wm * 2 + 1) * 32768 + (size_t)l * 16;
    const char* bBase0 = (const char*)BT + (size_t)(nb * 8 + wn * 4 + 0) * 32768 + (size_t)l * 16;
    const char* bBase1 = bBase0 + 32768;
    const char* bBase2 = bBase0 + 65536;
    const char* bBase3 = bBase0 + 98304;

    f32x16 acc[2][4];
#pragma unroll
    for (int m = 0; m < 2; ++m)
#pragma unroll
        for (int n = 0; n < 4; ++n)
#pragma unroll
            for (int i = 0; i < 16; ++i) acc[m][n][i] = 0.f;

#define LOADSET(A0, A1, B0, B1, B2, B3, S) do { \
    size_t o_ = (size_t)(S) * 1024; \
    A0 = *(const short8*)(aBase0 + o_); \
    A1 = *(const short8*)(aBase1 + o_); \
    B0 = *(const short8*)(bBase0 + o_); \
    B1 = *(const short8*)(bBase1 + o_); \
    B2 = *(const short8*)(bBase2 + o_); \
    B3 = *(const short8*)(bBase3 + o_); \
} while (0)

#define MFMASET(A0, A1, B0, B1, B2, B3) do { \
    __builtin_amdgcn_s_setprio(1); \
    acc[0][0] = __builtin_amdgcn_mfma_f32_32x32x16_bf16(A0, B0, acc[0][0], 0, 0, 0); \
    acc[0][1] = __builtin_amdgcn_mfma_f32_32x32x16_bf16(A0, B1, acc[0][1], 0, 0, 0); \
    acc[0][2] = __builtin_amdgcn_mfma_f32_32x32x16_bf16(A0, B2, acc[0][2], 0, 0, 0); \
    acc[0][3] = __builtin_amdgcn_mfma_f32_32x32x16_bf16(A0, B3, acc[0][3], 0, 0, 0); \
    acc[1][0] = __builtin_amdgcn_mfma_f32_32x32x16_bf16(A1, B0, acc[1][0], 0, 0, 0); \
    acc[1][1] = __builtin_amdgcn_mfma_f32_32x32x16_bf16(A1, B1, acc[1][1], 0, 0, 0); \
    acc[1][2] = __builtin_amdgcn_mfma_f32_32x32x16_bf16(A1, B2, acc[1][2], 0, 0, 0); \
    acc[1][3] = __builtin_amdgcn_mfma_f32_32x32x16_bf16(A1, B3, acc[1][3], 0, 0, 0); \
    __builtin_amdgcn_s_setprio(0); \
} while (0)

    // 2-deep register double buffer: p = even tiles, q = odd tiles (static names, rule #20)
    short8 pa0, pa1, pb0, pb1, pb2, pb3;
    short8 qa0, qa1, qb0, qb1, qb2, qb3;

    LOADSET(pa0, pa1, pb0, pb1, pb2, pb3, 0);
#pragma unroll 1
    for (int s = 0; s < 16; ++s) {
        LOADSET(qa0, qa1, qb0, qb1, qb2, qb3, 2 * s + 1);   // prefetch odd tile
        MFMASET(pa0, pa1, pb0, pb1, pb2, pb3);              // compute even tile
        if (s < 15) LOADSET(pa0, pa1, pb0, pb1, pb2, pb3, 2 * s + 2);  // prefetch even tile
        MFMASET(qa0, qa1, qb0, qb1, qb2, qb3);              // compute odd tile
    }

    // Epilogue: wave owns a full 128-col half (hb = nb*2+wn). Per row: top-2 + argmax,
    // wave-local (4 frags + 32-lane shuffle reduce), direct global write.
    // D layout: col(j)=lane&31, row=(r&3)+8*(r>>2)+4*(lane>>5).
    int colb = nb * 256 + wn * 128 + (l & 31);
#pragma unroll
    for (int m = 0; m < 2; ++m) {
#pragma unroll
        for (int r = 0; r < 16; ++r) {
            float v0 = acc[m][0][r], v1f = acc[m][1][r];
            float v2f = acc[m][2][r], v3f = acc[m][3][r];
            float p1, p2; int pi;
            if (v1f > v0)  { p1 = v1f; pi = 1; p2 = v0; }  else { p1 = v0;  pi = 0; p2 = v1f; }
            float q1, q2; int qi;
            if (v3f > v2f) { q1 = v3f; qi = 3; q2 = v2f; } else { q1 = v2f; qi = 2; q2 = v3f; }
            float w1, w2; int wi;
            if (q1 > p1) { w1 = q1; wi = qi; w2 = fmaxf(p1, q2); }
            else         { w1 = p1; wi = pi; w2 = fmaxf(q1, p2); }
            int ci = colb + wi * 32;
#pragma unroll
            for (int o = 1; o <= 16; o <<= 1) {
                float o1 = __shfl_xor(w1, o);
                float o2 = __shfl_xor(w2, o);
                int   oi = __shfl_xor(ci, o);
                if (o1 > w1) { w2 = fmaxf(w1, o2); w1 = o1; ci = oi; }
                else         { w2 = fmaxf(w2, o1); }
            }
            if ((l & 31) == r) {
                int rl = wm * 64 + m * 32 + (r & 3) + 8 * (r >> 2) + 4 * khalf;
                size_t rowg = (size_t)mb * 128 + rl;
                int hb = nb * 2 + wn;
                bm1[rowg * 64 + hb] = w1;
                bm2[rowg * 64 + hb] = w2;
                bi1[rowg * 64 + hb] = ci;
            }
        }
    }
}

// ---------------- K4: exact fp32-chain rescan of candidates; writes idx (bit-exact np argmin)
__global__ __launch_bounds__(64) void k_rescan(const float* __restrict__ z,
                                               const float* __restrict__ cb,
                                               const float* __restrict__ zz,
                                               const float* __restrict__ bm1,
                                               const float* __restrict__ bm2,
                                               const int* __restrict__ bi1,
                                               int* __restrict__ widx,
                                               float* __restrict__ out_idx) {
    __shared__ float a2[512];
    int row = blockIdx.x;
    int t = threadIdx.x;
    float v1 = bm1[(size_t)row * 64 + t];
    float v2 = bm2[(size_t)row * 64 + t];
    int   i1 = bi1[(size_t)row * 64 + t];
    float M = v1;
#pragma unroll
    for (int o = 1; o <= 32; o <<= 1) M = fmaxf(M, __shfl_xor(M, o));
    float th = M - THRESH;

    const float* zp = z + (size_t)(row >> 12) * CCH * HW + (row & 4095);
    for (int k = t; k < 512; k += 64) a2[k] = 2.0f * zp[(size_t)k * HW];
    float zzv = zz[row];
    __syncthreads();

    float bC = 3.0e38f;
    int bj = 0x7FFFFFFF;
    bool fullF = (v2 >= th);
    if (v1 >= th && !fullF) {
        const float* cr = cb + (size_t)i1 * CCH;
        float acc = 0.0f;
        for (int k = 0; k < 512; ++k) acc = __fmaf_rn(a2[k], cr[k], acc);
        bC = __fsub_rn(zzv, acc);
        bj = i1;
    }
    unsigned long long fm = __ballot(fullF);
    while (fm) {
        int nb2 = __ffsll(fm) - 1;
        fm &= fm - 1;
#pragma unroll
        for (int h = 0; h < 2; ++h) {
            int j = nb2 * 128 + h * 64 + t;
            const float* cr = cb + (size_t)j * CCH;
            float acc = 0.0f;
            for (int k = 0; k < 512; ++k) acc = __fmaf_rn(a2[k], cr[k], acc);
            float C = __fsub_rn(zzv, acc);
            if (C < bC || (C == bC && j < bj)) { bC = C; bj = j; }
        }
    }
#pragma unroll
    for (int o = 1; o <= 32; o <<= 1) {
        float oC = __shfl_xor(bC, o);
        int   oj = __shfl_xor(bj, o);
        if (oC < bC || (oC == bC && oj < bj)) { bC = oC; bj = oj; }
    }
    if (t == 0) { widx[row] = bj; out_idx[row] = (float)bj; }
}

// ---------------- K5: gather z_q, write z_q_st, accumulate loss numerator
__global__ __launch_bounds__(256) void k_out(const float* __restrict__ z,
                                             const float* __restrict__ cb,
                                             const float* __restrict__ m,
                                             const int* __restrict__ widx,
                                             float* __restrict__ out0,
                                             double* __restrict__ accs) {
    __shared__ float T[64 * 65];
    __shared__ float ls[4];
    int tid = threadIdx.x;
    int lhw = tid & 63, grp = tid >> 6;
    int bn = blockIdx.x >> 3, bc = blockIdx.x & 7;
    int n0 = bn * 64, c0 = bc * 64;
    int b = n0 >> 12, hw0 = n0 & 4095;
    const float* zb = z + (size_t)b * CCH * HW + hw0;
#pragma unroll
    for (int i = 0; i < 16; ++i) {
        int cl = grp + 4 * i;
        T[cl * 65 + lhw] = zb[(size_t)(c0 + cl) * HW + lhw];
    }
    __syncthreads();
    float la = 0.0f;
#pragma unroll
    for (int i = 0; i < 16; ++i) {
        int nl = grp + 4 * i;
        int n = n0 + nl;
        float zf = T[lhw * 65 + nl];
        int id = widx[n];
        float zq = cb[(size_t)id * CCH + c0 + lhw];
        float d = zq - zf;
        out0[(size_t)n * CCH + c0 + lhw] = zf + d;
        if (m[n] == 0.0f) la = fmaf(d, d, la);
    }
#pragma unroll
    for (int o = 32; o; o >>= 1) la += __shfl_xor(la, o);
    if ((tid & 63) == 0) ls[tid >> 6] = la;
    __syncthreads();
    if (tid == 0) atomicAdd(&accs[0], (double)(ls[0] + ls[1] + ls[2] + ls[3]));
}

// ---------------- K6: finalize loss = (1 + BETA) * mse
__global__ void k_final(const double* __restrict__ accs, float* __restrict__ outl) {
    double num = accs[0], wsum = accs[1];
    double denom = wsum * 512.0;
    double l1 = num / denom;
    outl[0] = (float)(l1 + 0.25 * l1);
}

extern "C" void kernel_launch(void* const* d_in, const int* in_sizes, int n_in,
                              void* d_out, int out_size, void* d_ws, size_t ws_size,
                              hipStream_t stream) {
    const float* z  = (const float*)d_in[0];
    const float* m  = (const float*)d_in[1];
    const float* cb = (const float*)d_in[2];
    float* out = (float*)d_out;
    char* ws = (char*)d_ws;

    unsigned short* BT   = (unsigned short*)(ws + WS_BT);
    float*  zzp  = (float*)(ws + WS_ZZ);
    float*  bm1  = (float*)(ws + WS_BM1);
    float*  bm2  = (float*)(ws + WS_BM2);
    int*    bi1  = (int*)(ws + WS_BI1);
    int*    widx = (int*)(ws + WS_IDX);
    double* accs = (double*)(ws + WS_ACC);

    float* out0    = out;
    float* outLoss = out + 16777216;
    float* outIdx  = out + 16777217;

    // AT scratch lives in the first 33.5MB of d_out (overwritten later by k_out).
    unsigned short* AT = (unsigned short*)out;

    hipLaunchKernelGGL(k_prep_b, dim3(2048), dim3(256), 0, stream, cb, BT, accs);
    hipLaunchKernelGGL(k_prep_a, dim3(8192), dim3(256), 0, stream, z, AT);
    hipLaunchKernelGGL(k_zz,     dim3(128),  dim3(256), 0, stream, z, zzp);
    hipLaunchKernelGGL(k_wsum,   dim3(32),   dim3(256), 0, stream, m, accs);
    hipLaunchKernelGGL(k_gemm,   dim3(8192), dim3(256), 0, stream, AT, BT, bm1, bm2, bi1);
    hipLaunchKernelGGL(k_rescan, dim3(32768), dim3(64), 0, stream, z, cb, zzp, bm1, bm2, bi1, widx, outIdx);
    hipLaunchKernelGGL(k_out,    dim3(4096), dim3(256), 0, stream, z, cb, m, widx, out0, accs);
    hipLaunchKernelGGL(k_final,  dim3(1),    dim3(1),   0, stream, accs, outLoss);
}

// Round 7
// 895.746 us; speedup vs baseline: 1.0989x; 1.0989x over previous
//
#include <hip/hip_runtime.h>
#include <math.h>

#define CCH 512
#define HW 4096
#define NN 32768
#define NE 8192

// ws layout (bytes)
#define WS_BT  0                         // BT bf16 fragment-order: 8192*512*2B = 8388608
#define WS_ZZ  (8388608)                 // zz f32 [32768]
#define WS_BM1 (WS_ZZ + 131072)          // blockmax v1 [32768][64] f32 = 8388608
#define WS_BM2 (WS_BM1 + 8388608)        // blockmax v2 [32768][64] f32
#define WS_BI1 (WS_BM2 + 8388608)        // blockmax i1 [32768][64] i32
#define WS_IDX (WS_BI1 + 8388608)        // final idx [32768] i32
#define WS_ACC (WS_IDX + 131072)         // accs[0]=loss num, accs[1]=wsum (f64)
// AT (bf16(2z) fragment-order, 32768*512*2B = 33.5MB) lives in d_out[0..8388608 floats):
// written by k_prep_a, last read by k_gemm, then overwritten by k_out. Sequential stream => safe.

// bf16-only GEMM: score error std ~2.7e-5; THRESH = 1e-3 >> 30 sigma guard.
#define THRESH 1.0e-3f

typedef __attribute__((ext_vector_type(8)))  short short8;   // 8 bf16 (4 VGPRs)
typedef __attribute__((ext_vector_type(16))) float f32x16;   // 32x32 MFMA acc

// ---------------- K0: cb -> BT bf16, fragment-linear layout; zero accs
// chunk(jt32, s): 64 lanes x 16B; lane l holds cb[j=jt*32+(l&31)][k=s*16+(l>>5)*8 + e], e=0..7
__global__ __launch_bounds__(256) void k_prep_b(const float* __restrict__ cb,
                                                unsigned short* __restrict__ BT,
                                                double* __restrict__ accs) {
    int t = blockIdx.x * 256 + threadIdx.x;
    if (t == 0) { accs[0] = 0.0; accs[1] = 0.0; }
    int l = t & 63, s = (t >> 6) & 31, jt = t >> 11;
    int j = jt * 32 + (l & 31);
    int kb = s * 16 + (l >> 5) * 8;
    short8 hv;
#pragma unroll
    for (int e = 0; e < 8; ++e) {
        float x = cb[(size_t)j * CCH + kb + e];
        hv[e] = (short)(__float_as_uint(x) >> 16);   // truncation to bf16
    }
    size_t chunk = (size_t)jt * 32 + s;
    *(short8*)&BT[chunk * 512 + (size_t)l * 8] = hv;
}

// ---------------- K0b: z -> AT = bf16(2z), same fragment-linear chunk layout as BT.
// chunk = mt*32+s; lane l holds 2z[m=mt*32+(l&31)][k=s*16+(l>>5)*8+e]
__global__ __launch_bounds__(256) void k_prep_a(const float* __restrict__ z,
                                                unsigned short* __restrict__ AT) {
    int t = blockIdx.x * 256 + threadIdx.x;
    int l = t & 63;
    int chunk = t >> 6;                  // [0, 32768)
    int mt = chunk >> 5, s = chunk & 31;
    int m = mt * 32 + (l & 31);
    int kb = s * 16 + (l >> 5) * 8;
    const float* zp = z + (size_t)(m >> 12) * CCH * HW + (m & 4095);
    short8 hv;
#pragma unroll
    for (int e = 0; e < 8; ++e) {
        float x = 2.0f * zp[(size_t)(kb + e) * HW];      // *2 exact (pow2)
        hv[e] = (short)(__float_as_uint(x) >> 16);       // truncation to bf16
    }
    *(short8*)&AT[(size_t)chunk * 512 + (size_t)l * 8] = hv;
}

// ---------------- K1: zz[n] = np.sum(zf*zf, axis=1), numpy's exact pairwise tree
__global__ __launch_bounds__(256) void k_zz(const float* __restrict__ z,
                                            float* __restrict__ zz) {
    int t = threadIdx.x;
    int n = blockIdx.x * 256 + t;
    int b = n >> 12, hw = n & 4095;
    const float* zp = z + (size_t)b * CCH * HW + hw;
    float blk[4];
#pragma unroll
    for (int q = 0; q < 4; ++q) {
        float r[8];
#pragma unroll
        for (int j = 0; j < 8; ++j) {
            float v = zp[(size_t)(q * 128 + j) * HW];
            r[j] = __fmul_rn(v, v);
        }
        for (int i = 8; i < 128; i += 8) {
#pragma unroll
            for (int j = 0; j < 8; ++j) {
                float v = zp[(size_t)(q * 128 + i + j) * HW];
                r[j] = __fadd_rn(r[j], __fmul_rn(v, v));
            }
        }
        blk[q] = __fadd_rn(__fadd_rn(__fadd_rn(r[0], r[1]), __fadd_rn(r[2], r[3])),
                           __fadd_rn(__fadd_rn(r[4], r[5]), __fadd_rn(r[6], r[7])));
    }
    zz[n] = __fadd_rn(__fadd_rn(blk[0], blk[1]), __fadd_rn(blk[2], blk[3]));
}

// ---------------- K2: wsum = sum(m==0)
__global__ __launch_bounds__(256) void k_wsum(const float* __restrict__ m,
                                              double* __restrict__ accs) {
    __shared__ int sc[4];
    int tid = threadIdx.x;
    int base = blockIdx.x * 1024;
    int cnt = 0;
#pragma unroll
    for (int k2 = 0; k2 < 4; ++k2) cnt += (m[base + k2 * 256 + tid] == 0.0f) ? 1 : 0;
#pragma unroll
    for (int o = 32; o; o >>= 1) cnt += __shfl_xor(cnt, o);
    if ((tid & 63) == 0) sc[tid >> 6] = cnt;
    __syncthreads();
    if (tid == 0) atomicAdd(&accs[1], (double)(sc[0] + sc[1] + sc[2] + sc[3]));
}

// ---------------- K3: LDS-FREE pre-packed bf16 MFMA GEMM (main loop unchanged from R5).
// Epilogue v2: LDS scatter/gather top-2 instead of 480 shuffle ops/wave.
// Per wave: 64 ds_write_b32 + 64 ds_read_b32, conflict-free ([32][65] padding).
// v2 is stored bf16-rounded-UP (upward bias => rescan full-block superset => safe).
__global__ __launch_bounds__(256, 2) void k_gemm(const unsigned short* __restrict__ AT,
                                                 const unsigned short* __restrict__ BT,
                                                 float* __restrict__ bm1,
                                                 float* __restrict__ bm2,
                                                 int* __restrict__ bi1) {
    __shared__ float    V1s[4][32][65];
    __shared__ unsigned PKs[4][32][65];
    int tid = threadIdx.x;
    int l = tid & 63;
    int gq = tid >> 6;             // wave id
    int wm = gq & 1, wn = gq >> 1; // 2x2 wave grid
    int nb = blockIdx.x & 31, mb = blockIdx.x >> 5;
    int khalf = l >> 5;

    // fragment-linear chunk bases (per-lane): row-tile chunks of 32 rows, 32 k-slices each
    const char* aBase0 = (const char*)AT + (size_t)(mb * 4 + wm * 2 + 0) * 32768 + (size_t)l * 16;
    const char* aBase1 = (const char*)AT + (size_t)(mb * 4 + wm * 2 + 1) * 32768 + (size_t)l * 16;
    const char* bBase0 = (const char*)BT + (size_t)(nb * 8 + wn * 4 + 0) * 32768 + (size_t)l * 16;
    const char* bBase1 = bBase0 + 32768;
    const char* bBase2 = bBase0 + 65536;
    const char* bBase3 = bBase0 + 98304;

    f32x16 acc[2][4];
#pragma unroll
    for (int m = 0; m < 2; ++m)
#pragma unroll
        for (int n = 0; n < 4; ++n)
#pragma unroll
            for (int i = 0; i < 16; ++i) acc[m][n][i] = 0.f;

#define LOADSET(A0, A1, B0, B1, B2, B3, S) do { \
    size_t o_ = (size_t)(S) * 1024; \
    A0 = *(const short8*)(aBase0 + o_); \
    A1 = *(const short8*)(aBase1 + o_); \
    B0 = *(const short8*)(bBase0 + o_); \
    B1 = *(const short8*)(bBase1 + o_); \
    B2 = *(const short8*)(bBase2 + o_); \
    B3 = *(const short8*)(bBase3 + o_); \
} while (0)

#define MFMASET(A0, A1, B0, B1, B2, B3) do { \
    __builtin_amdgcn_s_setprio(1); \
    acc[0][0] = __builtin_amdgcn_mfma_f32_32x32x16_bf16(A0, B0, acc[0][0], 0, 0, 0); \
    acc[0][1] = __builtin_amdgcn_mfma_f32_32x32x16_bf16(A0, B1, acc[0][1], 0, 0, 0); \
    acc[0][2] = __builtin_amdgcn_mfma_f32_32x32x16_bf16(A0, B2, acc[0][2], 0, 0, 0); \
    acc[0][3] = __builtin_amdgcn_mfma_f32_32x32x16_bf16(A0, B3, acc[0][3], 0, 0, 0); \
    acc[1][0] = __builtin_amdgcn_mfma_f32_32x32x16_bf16(A1, B0, acc[1][0], 0, 0, 0); \
    acc[1][1] = __builtin_amdgcn_mfma_f32_32x32x16_bf16(A1, B1, acc[1][1], 0, 0, 0); \
    acc[1][2] = __builtin_amdgcn_mfma_f32_32x32x16_bf16(A1, B2, acc[1][2], 0, 0, 0); \
    acc[1][3] = __builtin_amdgcn_mfma_f32_32x32x16_bf16(A1, B3, acc[1][3], 0, 0, 0); \
    __builtin_amdgcn_s_setprio(0); \
} while (0)

    // 2-deep register double buffer: p = even tiles, q = odd tiles (static names, rule #20)
    short8 pa0, pa1, pb0, pb1, pb2, pb3;
    short8 qa0, qa1, qb0, qb1, qb2, qb3;

    LOADSET(pa0, pa1, pb0, pb1, pb2, pb3, 0);
#pragma unroll 1
    for (int s = 0; s < 16; ++s) {
        LOADSET(qa0, qa1, qb0, qb1, qb2, qb3, 2 * s + 1);   // prefetch odd tile
        MFMASET(pa0, pa1, pb0, pb1, pb2, pb3);              // compute even tile
        if (s < 15) LOADSET(pa0, pa1, pb0, pb1, pb2, pb3, 2 * s + 2);  // prefetch even tile
        MFMASET(qa0, qa1, qb0, qb1, qb2, qb3);              // compute odd tile
    }

    // ---- Epilogue v2: LDS scatter/gather top-2 + argmax over this wave's 128-col half.
    // Phase 1: per lane, 4:1 n-reduce (exact f32, same tie rules as before); scatter
    //   (v1, pack{v2_bf16_up, wi}) to [cand=cl][row] in the wave's private LDS region.
    // Phase 2: lane l owns row l; serial merge of 32 candidates; direct global write.
    // Wave-local LDS only => no barrier needed (lgkmcnt ordering within wave).
    float    (*V1)[65] = V1s[gq];
    unsigned (*PK)[65] = PKs[gq];
    int cl = l & 31;
#pragma unroll
    for (int m = 0; m < 2; ++m) {
#pragma unroll
        for (int r = 0; r < 16; ++r) {
            float v0 = acc[m][0][r], v1f = acc[m][1][r];
            float v2f = acc[m][2][r], v3f = acc[m][3][r];
            float p1, p2; int pi;
            if (v1f > v0)  { p1 = v1f; pi = 1; p2 = v0; }  else { p1 = v0;  pi = 0; p2 = v1f; }
            float q1, q2; int qi;
            if (v3f > v2f) { q1 = v3f; qi = 3; q2 = v2f; } else { q1 = v2f; qi = 2; q2 = v3f; }
            float w1, w2; int wi;
            if (q1 > p1) { w1 = q1; wi = qi; w2 = fmaxf(p1, q2); }
            else         { w1 = p1; wi = pi; w2 = fmaxf(q1, p2); }
            // v2 -> bf16 rounded toward +inf (upward bias only), wi in low 2 bits
            unsigned u = __float_as_uint(w2);
            unsigned inc = (u & 0x80000000u) ? 0u : 0xFFFFu;
            unsigned pk = ((u + inc) & 0xFFFF0000u) | (unsigned)wi;
            int rowL = m * 32 + (r & 3) + 8 * (r >> 2) + 4 * khalf;   // 0..63 within wave tile
            V1[cl][rowL] = w1;
            PK[cl][rowL] = pk;
        }
    }
    // Phase 2: serial merge (row = lane id)
    float bv1 = V1[0][l];
    unsigned bpk = PK[0][l];
    float bv2 = __uint_as_float(bpk & 0xFFFF0000u);
    int bci = (int)(bpk & 3u) * 32 + 0;
#pragma unroll
    for (int c = 1; c < 32; ++c) {
        float nv1 = V1[c][l];
        unsigned npk = PK[c][l];
        float nv2 = __uint_as_float(npk & 0xFFFF0000u);
        int nci = (int)(npk & 3u) * 32 + c;
        if (nv1 > bv1) { bv2 = fmaxf(bv1, nv2); bv1 = nv1; bci = nci; }
        else           { bv2 = fmaxf(bv2, nv1); }
    }
    int hb = nb * 2 + wn;
    size_t rowg = (size_t)mb * 128 + wm * 64 + l;
    bm1[rowg * 64 + hb] = bv1;
    bm2[rowg * 64 + hb] = bv2;
    bi1[rowg * 64 + hb] = nb * 256 + wn * 128 + bci;
}

// ---------------- K4: exact fp32-chain rescan of candidates; writes idx (bit-exact np argmin)
__global__ __launch_bounds__(64) void k_rescan(const float* __restrict__ z,
                                               const float* __restrict__ cb,
                                               const float* __restrict__ zz,
                                               const float* __restrict__ bm1,
                                               const float* __restrict__ bm2,
                                               const int* __restrict__ bi1,
                                               int* __restrict__ widx,
                                               float* __restrict__ out_idx) {
    __shared__ float a2[512];
    int row = blockIdx.x;
    int t = threadIdx.x;
    float v1 = bm1[(size_t)row * 64 + t];
    float v2 = bm2[(size_t)row * 64 + t];
    int   i1 = bi1[(size_t)row * 64 + t];
    float M = v1;
#pragma unroll
    for (int o = 1; o <= 32; o <<= 1) M = fmaxf(M, __shfl_xor(M, o));
    float th = M - THRESH;

    const float* zp = z + (size_t)(row >> 12) * CCH * HW + (row & 4095);
    for (int k = t; k < 512; k += 64) a2[k] = 2.0f * zp[(size_t)k * HW];
    float zzv = zz[row];
    __syncthreads();

    float bC = 3.0e38f;
    int bj = 0x7FFFFFFF;
    bool fullF = (v2 >= th);
    if (v1 >= th && !fullF) {
        const float* cr = cb + (size_t)i1 * CCH;
        float acc = 0.0f;
        for (int k = 0; k < 512; ++k) acc = __fmaf_rn(a2[k], cr[k], acc);
        bC = __fsub_rn(zzv, acc);
        bj = i1;
    }
    unsigned long long fm = __ballot(fullF);
    while (fm) {
        int nb2 = __ffsll(fm) - 1;
        fm &= fm - 1;
#pragma unroll
        for (int h = 0; h < 2; ++h) {
            int j = nb2 * 128 + h * 64 + t;
            const float* cr = cb + (size_t)j * CCH;
            float acc = 0.0f;
            for (int k = 0; k < 512; ++k) acc = __fmaf_rn(a2[k], cr[k], acc);
            float C = __fsub_rn(zzv, acc);
            if (C < bC || (C == bC && j < bj)) { bC = C; bj = j; }
        }
    }
#pragma unroll
    for (int o = 1; o <= 32; o <<= 1) {
        float oC = __shfl_xor(bC, o);
        int   oj = __shfl_xor(bj, o);
        if (oC < bC || (oC == bC && oj < bj)) { bC = oC; bj = oj; }
    }
    if (t == 0) { widx[row] = bj; out_idx[row] = (float)bj; }
}

// ---------------- K5: gather z_q, write z_q_st, accumulate loss numerator
__global__ __launch_bounds__(256) void k_out(const float* __restrict__ z,
                                             const float* __restrict__ cb,
                                             const float* __restrict__ m,
                                             const int* __restrict__ widx,
                                             float* __restrict__ out0,
                                             double* __restrict__ accs) {
    __shared__ float T[64 * 65];
    __shared__ float ls[4];
    int tid = threadIdx.x;
    int lhw = tid & 63, grp = tid >> 6;
    int bn = blockIdx.x >> 3, bc = blockIdx.x & 7;
    int n0 = bn * 64, c0 = bc * 64;
    int b = n0 >> 12, hw0 = n0 & 4095;
    const float* zb = z + (size_t)b * CCH * HW + hw0;
#pragma unroll
    for (int i = 0; i < 16; ++i) {
        int cl = grp + 4 * i;
        T[cl * 65 + lhw] = zb[(size_t)(c0 + cl) * HW + lhw];
    }
    __syncthreads();
    float la = 0.0f;
#pragma unroll
    for (int i = 0; i < 16; ++i) {
        int nl = grp + 4 * i;
        int n = n0 + nl;
        float zf = T[lhw * 65 + nl];
        int id = widx[n];
        float zq = cb[(size_t)id * CCH + c0 + lhw];
        float d = zq - zf;
        out0[(size_t)n * CCH + c0 + lhw] = zf + d;
        if (m[n] == 0.0f) la = fmaf(d, d, la);
    }
#pragma unroll
    for (int o = 32; o; o >>= 1) la += __shfl_xor(la, o);
    if ((tid & 63) == 0) ls[tid >> 6] = la;
    __syncthreads();
    if (tid == 0) atomicAdd(&accs[0], (double)(ls[0] + ls[1] + ls[2] + ls[3]));
}

// ---------------- K6: finalize loss = (1 + BETA) * mse
__global__ void k_final(const double* __restrict__ accs, float* __restrict__ outl) {
    double num = accs[0], wsum = accs[1];
    double denom = wsum * 512.0;
    double l1 = num / denom;
    outl[0] = (float)(l1 + 0.25 * l1);
}

extern "C" void kernel_launch(void* const* d_in, const int* in_sizes, int n_in,
                              void* d_out, int out_size, void* d_ws, size_t ws_size,
                              hipStream_t stream) {
    const float* z  = (const float*)d_in[0];
    const float* m  = (const float*)d_in[1];
    const float* cb = (const float*)d_in[2];
    float* out = (float*)d_out;
    char* ws = (char*)d_ws;

    unsigned short* BT   = (unsigned short*)(ws + WS_BT);
    float*  zzp  = (float*)(ws + WS_ZZ);
    float*  bm1  = (float*)(ws + WS_BM1);
    float*  bm2  = (float*)(ws + WS_BM2);
    int*    bi1  = (int*)(ws + WS_BI1);
    int*    widx = (int*)(ws + WS_IDX);
    double* accs = (double*)(ws + WS_ACC);

    float* out0    = out;
    float* outLoss = out + 16777216;
    float* outIdx  = out + 16777217;

    // AT scratch lives in the first 33.5MB of d_out (overwritten later by k_out).
    unsigned short* AT = (unsigned short*)out;

    hipLaunchKernelGGL(k_prep_b, dim3(2048), dim3(256), 0, stream, cb, BT, accs);
    hipLaunchKernelGGL(k_prep_a, dim3(8192), dim3(256), 0, stream, z, AT);
    hipLaunchKernelGGL(k_zz,     dim3(128),  dim3(256), 0, stream, z, zzp);
    hipLaunchKernelGGL(k_wsum,   dim3(32),   dim3(256), 0, stream, m, accs);
    hipLaunchKernelGGL(k_gemm,   dim3(8192), dim3(256), 0, stream, AT, BT, bm1, bm2, bi1);
    hipLaunchKernelGGL(k_rescan, dim3(32768), dim3(64), 0, stream, z, cb, zzp, bm1, bm2, bi1, widx, outIdx);
    hipLaunchKernelGGL(k_out,    dim3(4096), dim3(256), 0, stream, z, cb, m, widx, out0, accs);
    hipLaunchKernelGGL(k_final,  dim3(1),    dim3(1),   0, stream, accs, outLoss);
}

// Round 8
// 808.825 us; speedup vs baseline: 1.2169x; 1.1075x over previous
//
#include <hip/hip_runtime.h>
#include <math.h>

#define CCH 512
#define HW 4096
#define NN 32768
#define NE 8192

// ws layout (bytes)
#define WS_BT  0                         // BT bf16 fragment-order: 8192*512*2B = 8388608
#define WS_ZZ  (8388608)                 // zz f32 [32768]
#define WS_BM1 (WS_ZZ + 131072)          // blockmax v1 [32768][64] f32 = 8388608
#define WS_BM2 (WS_BM1 + 8388608)        // blockmax v2 [32768][64] f32
#define WS_BI1 (WS_BM2 + 8388608)        // blockmax i1 [32768][64] i32
#define WS_IDX (WS_BI1 + 8388608)        // final idx [32768] i32
#define WS_ACC (WS_IDX + 131072)         // accs[0]=loss num, accs[1]=wsum (f64)
// d_out reuse: AT (bf16(2z) fragment-order, 33.5MB) lives in out[0..) for k_gemm;
// after k_gemm, k_prep_zt overwrites the region with ZT = z transposed [n][c] f32 (64MB)
// for k_rescan's coalesced row reads; k_out finally overwrites with z_q_st. Same-stream => safe.

// bf16-only GEMM: score error std ~2.7e-5; THRESH = 1e-3 >> 30 sigma guard.
#define THRESH 1.0e-3f

typedef __attribute__((ext_vector_type(8)))  short short8;   // 8 bf16 (4 VGPRs)
typedef __attribute__((ext_vector_type(16))) float f32x16;   // 32x32 MFMA acc

// ---------------- K0: cb -> BT bf16, fragment-linear layout; zero accs
// chunk(jt32, s): 64 lanes x 16B; lane l holds cb[j=jt*32+(l&31)][k=s*16+(l>>5)*8 + e], e=0..7
__global__ __launch_bounds__(256) void k_prep_b(const float* __restrict__ cb,
                                                unsigned short* __restrict__ BT,
                                                double* __restrict__ accs) {
    int t = blockIdx.x * 256 + threadIdx.x;
    if (t == 0) { accs[0] = 0.0; accs[1] = 0.0; }
    int l = t & 63, s = (t >> 6) & 31, jt = t >> 11;
    int j = jt * 32 + (l & 31);
    int kb = s * 16 + (l >> 5) * 8;
    short8 hv;
#pragma unroll
    for (int e = 0; e < 8; ++e) {
        float x = cb[(size_t)j * CCH + kb + e];
        hv[e] = (short)(__float_as_uint(x) >> 16);   // truncation to bf16
    }
    size_t chunk = (size_t)jt * 32 + s;
    *(short8*)&BT[chunk * 512 + (size_t)l * 8] = hv;
}

// ---------------- K0b: z -> AT = bf16(2z), same fragment-linear chunk layout as BT.
// chunk = mt*32+s; lane l holds 2z[m=mt*32+(l&31)][k=s*16+(l>>5)*8+e]
__global__ __launch_bounds__(256) void k_prep_a(const float* __restrict__ z,
                                                unsigned short* __restrict__ AT) {
    int t = blockIdx.x * 256 + threadIdx.x;
    int l = t & 63;
    int chunk = t >> 6;                  // [0, 32768)
    int mt = chunk >> 5, s = chunk & 31;
    int m = mt * 32 + (l & 31);
    int kb = s * 16 + (l >> 5) * 8;
    const float* zp = z + (size_t)(m >> 12) * CCH * HW + (m & 4095);
    short8 hv;
#pragma unroll
    for (int e = 0; e < 8; ++e) {
        float x = 2.0f * zp[(size_t)(kb + e) * HW];      // *2 exact (pow2)
        hv[e] = (short)(__float_as_uint(x) >> 16);       // truncation to bf16
    }
    *(short8*)&AT[(size_t)chunk * 512 + (size_t)l * 8] = hv;
}

// ---------------- K1: zz[n] = np.sum(zf*zf, axis=1), numpy's exact pairwise tree
__global__ __launch_bounds__(256) void k_zz(const float* __restrict__ z,
                                            float* __restrict__ zz) {
    int t = threadIdx.x;
    int n = blockIdx.x * 256 + t;
    int b = n >> 12, hw = n & 4095;
    const float* zp = z + (size_t)b * CCH * HW + hw;
    float blk[4];
#pragma unroll
    for (int q = 0; q < 4; ++q) {
        float r[8];
#pragma unroll
        for (int j = 0; j < 8; ++j) {
            float v = zp[(size_t)(q * 128 + j) * HW];
            r[j] = __fmul_rn(v, v);
        }
        for (int i = 8; i < 128; i += 8) {
#pragma unroll
            for (int j = 0; j < 8; ++j) {
                float v = zp[(size_t)(q * 128 + i + j) * HW];
                r[j] = __fadd_rn(r[j], __fmul_rn(v, v));
            }
        }
        blk[q] = __fadd_rn(__fadd_rn(__fadd_rn(r[0], r[1]), __fadd_rn(r[2], r[3])),
                           __fadd_rn(__fadd_rn(r[4], r[5]), __fadd_rn(r[6], r[7])));
    }
    zz[n] = __fadd_rn(__fadd_rn(blk[0], blk[1]), __fadd_rn(blk[2], blk[3]));
}

// ---------------- K2: wsum = sum(m==0)
__global__ __launch_bounds__(256) void k_wsum(const float* __restrict__ m,
                                              double* __restrict__ accs) {
    __shared__ int sc[4];
    int tid = threadIdx.x;
    int base = blockIdx.x * 1024;
    int cnt = 0;
#pragma unroll
    for (int k2 = 0; k2 < 4; ++k2) cnt += (m[base + k2 * 256 + tid] == 0.0f) ? 1 : 0;
#pragma unroll
    for (int o = 32; o; o >>= 1) cnt += __shfl_xor(cnt, o);
    if ((tid & 63) == 0) sc[tid >> 6] = cnt;
    __syncthreads();
    if (tid == 0) atomicAdd(&accs[1], (double)(sc[0] + sc[1] + sc[2] + sc[3]));
}

// ---------------- K3: LDS-FREE pre-packed bf16 MFMA GEMM.
// Epilogue v2: LDS scatter/gather top-2 (conflict-free [32][65] padding).
// v2 stored bf16-rounded-UP (upward bias => rescan full-block superset => safe).
__global__ __launch_bounds__(256, 2) void k_gemm(const unsigned short* __restrict__ AT,
                                                 const unsigned short* __restrict__ BT,
                                                 float* __restrict__ bm1,
                                                 float* __restrict__ bm2,
                                                 int* __restrict__ bi1) {
    __shared__ float    V1s[4][32][65];
    __shared__ unsigned PKs[4][32][65];
    int tid = threadIdx.x;
    int l = tid & 63;
    int gq = tid >> 6;             // wave id
    int wm = gq & 1, wn = gq >> 1; // 2x2 wave grid
    int nb = blockIdx.x & 31, mb = blockIdx.x >> 5;
    int khalf = l >> 5;

    // fragment-linear chunk bases (per-lane): row-tile chunks of 32 rows, 32 k-slices each
    const char* aBase0 = (const char*)AT + (size_t)(mb * 4 + wm * 2 + 0) * 32768 + (size_t)l * 16;
    const char* aBase1 = (const char*)AT + (size_t)(mb * 4 + wm * 2 + 1) * 32768 + (size_t)l * 16;
    const char* bBase0 = (const char*)BT + (size_t)(nb * 8 + wn * 4 + 0) * 32768 + (size_t)l * 16;
    const char* bBase1 = bBase0 + 32768;
    const char* bBase2 = bBase0 + 65536;
    const char* bBase3 = bBase0 + 98304;

    f32x16 acc[2][4];
#pragma unroll
    for (int m = 0; m < 2; ++m)
#pragma unroll
        for (int n = 0; n < 4; ++n)
#pragma unroll
            for (int i = 0; i < 16; ++i) acc[m][n][i] = 0.f;

#define LOADSET(A0, A1, B0, B1, B2, B3, S) do { \
    size_t o_ = (size_t)(S) * 1024; \
    A0 = *(const short8*)(aBase0 + o_); \
    A1 = *(const short8*)(aBase1 + o_); \
    B0 = *(const short8*)(bBase0 + o_); \
    B1 = *(const short8*)(bBase1 + o_); \
    B2 = *(const short8*)(bBase2 + o_); \
    B3 = *(const short8*)(bBase3 + o_); \
} while (0)

#define MFMASET(A0, A1, B0, B1, B2, B3) do { \
    __builtin_amdgcn_s_setprio(1); \
    acc[0][0] = __builtin_amdgcn_mfma_f32_32x32x16_bf16(A0, B0, acc[0][0], 0, 0, 0); \
    acc[0][1] = __builtin_amdgcn_mfma_f32_32x32x16_bf16(A0, B1, acc[0][1], 0, 0, 0); \
    acc[0][2] = __builtin_amdgcn_mfma_f32_32x32x16_bf16(A0, B2, acc[0][2], 0, 0, 0); \
    acc[0][3] = __builtin_amdgcn_mfma_f32_32x32x16_bf16(A0, B3, acc[0][3], 0, 0, 0); \
    acc[1][0] = __builtin_amdgcn_mfma_f32_32x32x16_bf16(A1, B0, acc[1][0], 0, 0, 0); \
    acc[1][1] = __builtin_amdgcn_mfma_f32_32x32x16_bf16(A1, B1, acc[1][1], 0, 0, 0); \
    acc[1][2] = __builtin_amdgcn_mfma_f32_32x32x16_bf16(A1, B2, acc[1][2], 0, 0, 0); \
    acc[1][3] = __builtin_amdgcn_mfma_f32_32x32x16_bf16(A1, B3, acc[1][3], 0, 0, 0); \
    __builtin_amdgcn_s_setprio(0); \
} while (0)

    // 2-deep register double buffer: p = even tiles, q = odd tiles (static names, rule #20)
    short8 pa0, pa1, pb0, pb1, pb2, pb3;
    short8 qa0, qa1, qb0, qb1, qb2, qb3;

    LOADSET(pa0, pa1, pb0, pb1, pb2, pb3, 0);
#pragma unroll 1
    for (int s = 0; s < 16; ++s) {
        LOADSET(qa0, qa1, qb0, qb1, qb2, qb3, 2 * s + 1);   // prefetch odd tile
        MFMASET(pa0, pa1, pb0, pb1, pb2, pb3);              // compute even tile
        if (s < 15) LOADSET(pa0, pa1, pb0, pb1, pb2, pb3, 2 * s + 2);  // prefetch even tile
        MFMASET(qa0, qa1, qb0, qb1, qb2, qb3);              // compute odd tile
    }

    // ---- Epilogue v2: LDS scatter/gather top-2 + argmax over this wave's 128-col half.
    float    (*V1)[65] = V1s[gq];
    unsigned (*PK)[65] = PKs[gq];
    int cl = l & 31;
#pragma unroll
    for (int m = 0; m < 2; ++m) {
#pragma unroll
        for (int r = 0; r < 16; ++r) {
            float v0 = acc[m][0][r], v1f = acc[m][1][r];
            float v2f = acc[m][2][r], v3f = acc[m][3][r];
            float p1, p2; int pi;
            if (v1f > v0)  { p1 = v1f; pi = 1; p2 = v0; }  else { p1 = v0;  pi = 0; p2 = v1f; }
            float q1, q2; int qi;
            if (v3f > v2f) { q1 = v3f; qi = 3; q2 = v2f; } else { q1 = v2f; qi = 2; q2 = v3f; }
            float w1, w2; int wi;
            if (q1 > p1) { w1 = q1; wi = qi; w2 = fmaxf(p1, q2); }
            else         { w1 = p1; wi = pi; w2 = fmaxf(q1, p2); }
            // v2 -> bf16 rounded toward +inf (upward bias only), wi in low 2 bits
            unsigned u = __float_as_uint(w2);
            unsigned inc = (u & 0x80000000u) ? 0u : 0xFFFFu;
            unsigned pk = ((u + inc) & 0xFFFF0000u) | (unsigned)wi;
            int rowL = m * 32 + (r & 3) + 8 * (r >> 2) + 4 * khalf;   // 0..63 within wave tile
            V1[cl][rowL] = w1;
            PK[cl][rowL] = pk;
        }
    }
    // Phase 2: serial merge (row = lane id)
    float bv1 = V1[0][l];
    unsigned bpk = PK[0][l];
    float bv2 = __uint_as_float(bpk & 0xFFFF0000u);
    int bci = (int)(bpk & 3u) * 32 + 0;
#pragma unroll
    for (int c = 1; c < 32; ++c) {
        float nv1 = V1[c][l];
        unsigned npk = PK[c][l];
        float nv2 = __uint_as_float(npk & 0xFFFF0000u);
        int nci = (int)(npk & 3u) * 32 + c;
        if (nv1 > bv1) { bv2 = fmaxf(bv1, nv2); bv1 = nv1; bci = nci; }
        else           { bv2 = fmaxf(bv2, nv1); }
    }
    int hb = nb * 2 + wn;
    size_t rowg = (size_t)mb * 128 + wm * 64 + l;
    bm1[rowg * 64 + hb] = bv1;
    bm2[rowg * 64 + hb] = bv2;
    bi1[rowg * 64 + hb] = nb * 256 + wn * 128 + bci;
}

// ---------------- K3b: z (NCHW) -> ZT [n][c] f32, coalesced both sides via LDS tile.
// Runs AFTER k_gemm (overwrites the AT region of d_out). Same structure as k_out's staging.
__global__ __launch_bounds__(256) void k_prep_zt(const float* __restrict__ z,
                                                 float* __restrict__ ZT) {
    __shared__ float T[64 * 65];
    int tid = threadIdx.x;
    int lhw = tid & 63, grp = tid >> 6;
    int bn = blockIdx.x >> 3, bc = blockIdx.x & 7;
    int n0 = bn * 64, c0 = bc * 64;
    int b = n0 >> 12, hw0 = n0 & 4095;
    const float* zb = z + (size_t)b * CCH * HW + hw0;
#pragma unroll
    for (int i = 0; i < 16; ++i) {
        int cl = grp + 4 * i;
        T[cl * 65 + lhw] = zb[(size_t)(c0 + cl) * HW + lhw];
    }
    __syncthreads();
#pragma unroll
    for (int i = 0; i < 16; ++i) {
        int nl = grp + 4 * i;
        ZT[(size_t)(n0 + nl) * CCH + c0 + lhw] = T[lhw * 65 + nl];
    }
}

// ---------------- K4: exact fp32-chain rescan of candidates; writes idx (bit-exact np argmin)
// a2 staged from ZT (row-contiguous, coalesced) instead of strided z reads.
__global__ __launch_bounds__(64) void k_rescan(const float* __restrict__ ZT,
                                               const float* __restrict__ cb,
                                               const float* __restrict__ zz,
                                               const float* __restrict__ bm1,
                                               const float* __restrict__ bm2,
                                               const int* __restrict__ bi1,
                                               int* __restrict__ widx,
                                               float* __restrict__ out_idx) {
    __shared__ float a2[512];
    int row = blockIdx.x;
    int t = threadIdx.x;
    float v1 = bm1[(size_t)row * 64 + t];
    float v2 = bm2[(size_t)row * 64 + t];
    int   i1 = bi1[(size_t)row * 64 + t];
    float M = v1;
#pragma unroll
    for (int o = 1; o <= 32; o <<= 1) M = fmaxf(M, __shfl_xor(M, o));
    float th = M - THRESH;

    const float* zrow = ZT + (size_t)row * CCH;
#pragma unroll
    for (int k = t; k < 512; k += 64) a2[k] = 2.0f * zrow[k];
    float zzv = zz[row];
    __syncthreads();

    float bC = 3.0e38f;
    int bj = 0x7FFFFFFF;
    bool fullF = (v2 >= th);
    if (v1 >= th && !fullF) {
        const float* cr = cb + (size_t)i1 * CCH;
        float acc = 0.0f;
        for (int k = 0; k < 512; ++k) acc = __fmaf_rn(a2[k], cr[k], acc);
        bC = __fsub_rn(zzv, acc);
        bj = i1;
    }
    unsigned long long fm = __ballot(fullF);
    while (fm) {
        int nb2 = __ffsll(fm) - 1;
        fm &= fm - 1;
#pragma unroll
        for (int h = 0; h < 2; ++h) {
            int j = nb2 * 128 + h * 64 + t;
            const float* cr = cb + (size_t)j * CCH;
            float acc = 0.0f;
            for (int k = 0; k < 512; ++k) acc = __fmaf_rn(a2[k], cr[k], acc);
            float C = __fsub_rn(zzv, acc);
            if (C < bC || (C == bC && j < bj)) { bC = C; bj = j; }
        }
    }
#pragma unroll
    for (int o = 1; o <= 32; o <<= 1) {
        float oC = __shfl_xor(bC, o);
        int   oj = __shfl_xor(bj, o);
        if (oC < bC || (oC == bC && oj < bj)) { bC = oC; bj = oj; }
    }
    if (t == 0) { widx[row] = bj; out_idx[row] = (float)bj; }
}

// ---------------- K5: gather z_q, write z_q_st, accumulate loss numerator
__global__ __launch_bounds__(256) void k_out(const float* __restrict__ z,
                                             const float* __restrict__ cb,
                                             const float* __restrict__ m,
                                             const int* __restrict__ widx,
                                             float* __restrict__ out0,
                                             double* __restrict__ accs) {
    __shared__ float T[64 * 65];
    __shared__ float ls[4];
    int tid = threadIdx.x;
    int lhw = tid & 63, grp = tid >> 6;
    int bn = blockIdx.x >> 3, bc = blockIdx.x & 7;
    int n0 = bn * 64, c0 = bc * 64;
    int b = n0 >> 12, hw0 = n0 & 4095;
    const float* zb = z + (size_t)b * CCH * HW + hw0;
#pragma unroll
    for (int i = 0; i < 16; ++i) {
        int cl = grp + 4 * i;
        T[cl * 65 + lhw] = zb[(size_t)(c0 + cl) * HW + lhw];
    }
    __syncthreads();
    float la = 0.0f;
#pragma unroll
    for (int i = 0; i < 16; ++i) {
        int nl = grp + 4 * i;
        int n = n0 + nl;
        float zf = T[lhw * 65 + nl];
        int id = widx[n];
        float zq = cb[(size_t)id * CCH + c0 + lhw];
        float d = zq - zf;
        out0[(size_t)n * CCH + c0 + lhw] = zf + d;
        if (m[n] == 0.0f) la = fmaf(d, d, la);
    }
#pragma unroll
    for (int o = 32; o; o >>= 1) la += __shfl_xor(la, o);
    if ((tid & 63) == 0) ls[tid >> 6] = la;
    __syncthreads();
    if (tid == 0) atomicAdd(&accs[0], (double)(ls[0] + ls[1] + ls[2] + ls[3]));
}

// ---------------- K6: finalize loss = (1 + BETA) * mse
__global__ void k_final(const double* __restrict__ accs, float* __restrict__ outl) {
    double num = accs[0], wsum = accs[1];
    double denom = wsum * 512.0;
    double l1 = num / denom;
    outl[0] = (float)(l1 + 0.25 * l1);
}

extern "C" void kernel_launch(void* const* d_in, const int* in_sizes, int n_in,
                              void* d_out, int out_size, void* d_ws, size_t ws_size,
                              hipStream_t stream) {
    const float* z  = (const float*)d_in[0];
    const float* m  = (const float*)d_in[1];
    const float* cb = (const float*)d_in[2];
    float* out = (float*)d_out;
    char* ws = (char*)d_ws;

    unsigned short* BT   = (unsigned short*)(ws + WS_BT);
    float*  zzp  = (float*)(ws + WS_ZZ);
    float*  bm1  = (float*)(ws + WS_BM1);
    float*  bm2  = (float*)(ws + WS_BM2);
    int*    bi1  = (int*)(ws + WS_BI1);
    int*    widx = (int*)(ws + WS_IDX);
    double* accs = (double*)(ws + WS_ACC);

    float* out0    = out;
    float* outLoss = out + 16777216;
    float* outIdx  = out + 16777217;

    // d_out scratch: AT (bf16 2z) for k_gemm, then ZT (f32 z^T) for k_rescan.
    unsigned short* AT = (unsigned short*)out;
    float*          ZT = out;

    hipLaunchKernelGGL(k_prep_b, dim3(2048), dim3(256), 0, stream, cb, BT, accs);
    hipLaunchKernelGGL(k_prep_a, dim3(8192), dim3(256), 0, stream, z, AT);
    hipLaunchKernelGGL(k_zz,     dim3(128),  dim3(256), 0, stream, z, zzp);
    hipLaunchKernelGGL(k_wsum,   dim3(32),   dim3(256), 0, stream, m, accs);
    hipLaunchKernelGGL(k_gemm,   dim3(8192), dim3(256), 0, stream, AT, BT, bm1, bm2, bi1);
    hipLaunchKernelGGL(k_prep_zt, dim3(4096), dim3(256), 0, stream, z, ZT);
    hipLaunchKernelGGL(k_rescan, dim3(32768), dim3(64), 0, stream, ZT, cb, zzp, bm1, bm2, bi1, widx, outIdx);
    hipLaunchKernelGGL(k_out,    dim3(4096), dim3(256), 0, stream, z, cb, m, widx, out0, accs);
    hipLaunchKernelGGL(k_final,  dim3(1),    dim3(1),   0, stream, accs, outLoss);
}